// Round 8
// baseline (127.699 us; speedup 1.0000x reference)
//
#include <hip/hip_runtime.h>
#include <math.h>

// (B,N,D,H) = (4, 2048, 1024, 64)
constexpr int kN = 2048;
constexpr int kD = 1024;

typedef __attribute__((ext_vector_type(8))) short bf16x8;
typedef __attribute__((ext_vector_type(4))) short bf16x4;
typedef __attribute__((ext_vector_type(4))) float f32x4;

#define MFMA(a, b, c) __builtin_amdgcn_mfma_f32_16x16x32_bf16(a, b, c, 0, 0, 0)

__device__ __forceinline__ short f2bf(float f) {
    unsigned u = __float_as_uint(f);
    u += 0x7fff + ((u >> 16) & 1);      // round-to-nearest-even
    return (short)(u >> 16);
}
__device__ __forceinline__ float bf2f(short s) {
    return __uint_as_float(((unsigned)(unsigned short)s) << 16);
}

// global->LDS direct DMA. LDS dest = wave-uniform base + lane*16.
__device__ __forceinline__ void g2l(void* lds, const void* g, int nbytes, int t) {
    int lane = t & 63, w = t >> 6;
    for (int base = w * 1024; base < nbytes; base += 4096) {
        if (base + lane * 16 < nbytes) {
            __builtin_amdgcn_global_load_lds(
                (const __attribute__((address_space(1))) void*)((const char*)g + base + lane * 16),
                (__attribute__((address_space(3))) void*)((char*)lds + base),
                16, 0, 0);
        }
    }
}

// ---------------------------------------------------------------------------
// prep: Wt in MFMA-fragment-contiguous layout (as round 7). bcat = bq|bk|bv.
// ---------------------------------------------------------------------------
__global__ __launch_bounds__(256) void prep_kernel(
        const float* __restrict__ Wq, const float* __restrict__ Wk,
        const float* __restrict__ Wv, const float* __restrict__ bq,
        const float* __restrict__ bk, const float* __restrict__ bv,
        short* __restrict__ Wt, float* __restrict__ bcat)
{
    int tid = blockIdx.x * 256 + threadIdx.x;
    int stride = gridDim.x * 256;
    for (int e = tid; e < 16 * 12 * 2 * 512; e += stride) {
        int kc = e / 12288;
        int rem = e - kc * 12288;
        int nt = rem >> 10;
        int r2 = rem & 1023;
        int f = r2 >> 9;
        int r3 = r2 & 511;
        int q8 = r3 >> 7;
        int l15 = (r3 >> 3) & 15;
        int el = r3 & 7;
        int n = nt * 16 + l15;
        int d = kc * 64 + f * 32 + q8 * 8 + el;
        float wv = (n < 64) ? Wq[d * 64 + n]
                 : (n < 128) ? Wk[d * 64 + (n - 64)]
                 : Wv[d * 64 + (n - 128)];
        Wt[e] = f2bf(wv);
    }
    if (tid < 192)
        bcat[tid] = (tid < 64) ? bq[tid] : (tid < 128) ? bk[tid - 64] : bv[tid - 128];
}

// ---------------------------------------------------------------------------
// qkv: 512 blocks x 16 rows. x staged to LDS once; W fragments direct
// global->VGPR. Outputs: gq/gk[8192][72] bf16 row-major;
// vt FRAGMENT-LINEAR: vt[(((bz*32+jt)*4 + ht)*2 + f)*512 + lane*8 + e]
//   = vtile[h = ht*16 + (lane&15)][j_local = f*32 + (lane>>4)*8 + e].
// ---------------------------------------------------------------------------
constexpr int XP = 1032;   // xs pitch (shorts)

__global__ __launch_bounds__(256) void qkv_kernel(
        const float* __restrict__ x, const short* __restrict__ Wt,
        const float* __restrict__ bcat,
        short* __restrict__ gq, short* __restrict__ gk, short* __restrict__ vt)
{
    __shared__ __align__(16) short xs[16 * XP];    // 33,024 B
    const int t = threadIdx.x;
    const int w = t >> 6, lane = t & 63, l15 = lane & 15, q8 = lane >> 4;
    const int m0 = blockIdx.x * 16;

    // stage x tile (16 rows x 1024), fp32 -> bf16, once
    {
        int row = t >> 4, c4 = (t & 15) * 4;
        const float* xr = x + (size_t)(m0 + row) * kD;
        #pragma unroll
        for (int cc = 0; cc < 16; ++cc) {
            float4 xv = *(const float4*)&xr[cc * 64 + c4];
            bf16x4 pk = {f2bf(xv.x), f2bf(xv.y), f2bf(xv.z), f2bf(xv.w)};
            *(bf16x4*)&xs[row * XP + cc * 64 + c4] = pk;
        }
    }
    __syncthreads();

    f32x4 acc[3];
    #pragma unroll
    for (int ct = 0; ct < 3; ++ct) acc[ct] = (f32x4){0.f, 0.f, 0.f, 0.f};

    #pragma unroll 4
    for (int kc = 0; kc < 16; ++kc) {
        bf16x8 a0 = *(const bf16x8*)&xs[l15 * XP + kc * 64 + q8 * 8];
        bf16x8 a1 = *(const bf16x8*)&xs[l15 * XP + kc * 64 + 32 + q8 * 8];
        #pragma unroll
        for (int ct = 0; ct < 3; ++ct) {
            int nt = w * 3 + ct;
            const short* bp = Wt + ((size_t)(kc * 12 + nt) * 2) * 512 + lane * 8;
            bf16x8 b0 = *(const bf16x8*)bp;
            bf16x8 b1 = *(const bf16x8*)(bp + 512);
            acc[ct] = MFMA(a0, b0, acc[ct]);
            acc[ct] = MFMA(a1, b1, acc[ct]);
        }
    }

    const int bz = m0 >> 11;
    const int jt = (m0 & 2047) >> 6;
    const int jb = m0 & 63;                // 0/16/32/48
    #pragma unroll
    for (int ct = 0; ct < 3; ++ct) {
        int nb2 = w * 48 + ct * 16;        // 16-tile lies in one region
        int n = nb2 + l15;
        float bias = bcat[n];
        if (nb2 < 64) {
            #pragma unroll
            for (int r = 0; r < 4; ++r)
                gq[(size_t)(m0 + q8 * 4 + r) * 72 + n] = f2bf(acc[ct][r] + bias);
        } else if (nb2 < 128) {
            #pragma unroll
            for (int r = 0; r < 4; ++r)
                gk[(size_t)(m0 + q8 * 4 + r) * 72 + (n - 64)] = f2bf(acc[ct][r] + bias);
        } else {
            int ht = (nb2 - 128) >> 4;
            int base_j = jb + q8 * 4;          // j_local of r=0
            int f = base_j >> 5;
            int q8f = (base_j >> 3) & 3;
            int e0 = base_j & 7;               // = 4*(q8&1)
            bf16x4 pk = {f2bf(acc[ct][0] + bias), f2bf(acc[ct][1] + bias),
                         f2bf(acc[ct][2] + bias), f2bf(acc[ct][3] + bias)};
            size_t addr = (((size_t)((bz * 32 + jt) * 4 + ht) * 2 + f) * 512)
                          + (q8f * 16 + l15) * 8 + e0;
            *(bf16x4*)&vt[addr] = pk;
        }
    }
}

// ---------------------------------------------------------------------------
// stats: l[j] partials + P materialization.
// P layout: lane-major subtiles:
//   Pm[(((((bz*32+jt)*32 + itg)*4 + jsub)*4 + isub)*256) + lane*4 + r]
//   holds p at j = jt*64 + jsub*16 + (lane>>4)*4 + r, i = itg*64 + isub*16 + (lane&15)
// Grid 512: b&3 = i-chunk(512), (b>>2)&3 = bz, b>>4 = j-tile(64). Max 8 iters.
// ---------------------------------------------------------------------------
__global__ __launch_bounds__(256) void stats_kernel(
        const short* __restrict__ gq, const short* __restrict__ gk,
        float* __restrict__ l2, short* __restrict__ Pm)
{
    __shared__ __align__(16) short qsm[64 * 72];
    __shared__ __align__(16) short ksm[2][64 * 72];
    const int t = threadIdx.x;
    const int w = t >> 6, lane = t & 63, l15 = lane & 15, q8 = lane >> 4;
    const int b = blockIdx.x;
    const int ic = b & 3, bz = (b >> 2) & 3, jt = b >> 4;
    const int j0 = jt * 64;
    const int ilo = ic * 512, ihi = ilo + 512;
    const int istart = (j0 > ilo) ? j0 : ilo;
    const int count = (istart < ihi) ? ((ihi - istart) >> 6) : 0;

    float lloc[4] = {0.f, 0.f, 0.f, 0.f};

    if (count > 0) {
        g2l(qsm, gq + (size_t)(bz * kN + j0) * 72, 64 * 144, t);
        g2l(ksm[0], gk + (size_t)(bz * kN + istart) * 72, 64 * 144, t);
        __syncthreads();
        int jrow = 16 * w + l15;
        bf16x8 a0 = *(const bf16x8*)&qsm[jrow * 72 + q8 * 8];
        bf16x8 a1 = *(const bf16x8*)&qsm[jrow * 72 + 32 + q8 * 8];

        for (int idx = 0; idx < count; ++idx) {
            const int cur = idx & 1;
            if (idx + 1 < count)
                g2l(ksm[cur ^ 1],
                    gk + (size_t)(bz * kN + istart + (idx + 1) * 64) * 72, 64 * 144, t);
            const int i0 = istart + idx * 64;
            const size_t tbase =
                (((size_t)(bz * 32 + jt) * 32 + (size_t)(i0 >> 6)) * 4 + w) * 4 * 256;
            #pragma unroll
            for (int it = 0; it < 4; ++it) {
                int irow = it * 16 + l15;
                bf16x8 b0 = *(const bf16x8*)&ksm[cur][irow * 72 + q8 * 8];
                bf16x8 b1 = *(const bf16x8*)&ksm[cur][irow * 72 + 32 + q8 * 8];
                f32x4 s = (f32x4){0.f, 0.f, 0.f, 0.f};
                s = MFMA(a0, b0, s);
                s = MFMA(a1, b1, s);
                int ig = i0 + it * 16 + l15;
                bf16x4 pk;
                #pragma unroll
                for (int r = 0; r < 4; ++r) {
                    int jg = j0 + 16 * w + q8 * 4 + r;
                    float sv = s[r];
                    float e = __expf(sv * 0.125f);
                    bool valid = (ig >= jg) && (sv != 0.0f);
                    lloc[r] += valid ? e : 0.0f;
                    pk[r] = valid ? f2bf(e) : (short)0;
                }
                *(bf16x4*)&Pm[tbase + it * 256 + lane * 4] = pk;
            }
            __syncthreads();
        }
    }
    #pragma unroll
    for (int off = 1; off < 16; off <<= 1)
        #pragma unroll
        for (int r = 0; r < 4; ++r)
            lloc[r] += __shfl_xor(lloc[r], off);
    if (l15 == 0) {
        #pragma unroll
        for (int r = 0; r < 4; ++r)
            l2[ic * 8192 + bz * kN + j0 + 16 * w + q8 * 4 + r] = lloc[r];
    }
}

// ---------------------------------------------------------------------------
// vscale: vt[h,j] *= 1/l[j] in place, fragment-linear layout.
// Grid 128 = bz*32+jt.
// ---------------------------------------------------------------------------
__global__ __launch_bounds__(256) void vscale_kernel(
        short* __restrict__ vt, const float* __restrict__ l2)
{
    __shared__ float rsm[64];
    const int g = blockIdx.x, t = threadIdx.x;
    if (t < 64) {
        int j = (g >> 5) * kN + (g & 31) * 64 + t;
        float l = l2[j] + l2[8192 + j] + l2[16384 + j] + l2[24576 + j];
        rsm[t] = (l > 0.f) ? 1.0f / l : 0.0f;
    }
    __syncthreads();
    const int slice = t >> 5;          // 0..7 = ht*2+f
    const int lane32 = t & 31;
    const int f = slice & 1;
    #pragma unroll
    for (int half = 0; half < 2; ++half) {
        int lidx = lane32 + half * 32;             // frag lane 0..63
        int q8v = lidx >> 4;
        size_t addr = ((size_t)g * 8 + slice) * 512 + lidx * 8;
        bf16x8 v = *(bf16x8*)&vt[addr];
        bf16x8 o;
        #pragma unroll
        for (int e = 0; e < 8; ++e) {
            int jl = f * 32 + q8v * 8 + e;
            o[e] = f2bf(bf2f(v[e]) * rsm[jl]);
        }
        *(bf16x8*)&vt[addr] = o;
    }
}

// ---------------------------------------------------------------------------
// out: pure GEMM over materialized P and pre-scaled vt. NO LDS, NO barriers.
// Grid 512: b&3 = jc(512-chunk), (b>>2)&3 = bz, b>>4 = i-tile(64). Max 8 iters.
// A-frags from Pm lane-major subtiles; B-frags from vt fragment-linear.
// ---------------------------------------------------------------------------
__global__ __launch_bounds__(256) void out_kernel(
        const short* __restrict__ Pm, const short* __restrict__ vt,
        float* __restrict__ part)
{
    const int t = threadIdx.x;
    const int w = t >> 6, lane = t & 63, l15 = lane & 15, q8 = lane >> 4;
    const int b = blockIdx.x;
    const int jc = b & 3, bz = (b >> 2) & 3, it = b >> 4;
    const int i0 = it * 64;
    const int jlo = jc * 512;
    const int jhi = (jlo + 512 < i0 + 64) ? (jlo + 512) : (i0 + 64);
    const int count = (jlo < jhi) ? ((jhi - jlo) >> 6) : 0;

    f32x4 oacc[4];
    #pragma unroll
    for (int i = 0; i < 4; ++i) oacc[i] = (f32x4){0.f, 0.f, 0.f, 0.f};

    // A-frag addressing within a (jt,it) tile:
    //   a0: subtile (jsub = q8>>1, isub = w), offsets aoff and aoff+64
    //   a1: same +2 jsubs (j_local 32..63)
    const int aoff = ((q8 >> 1) * 4 + w) * 256 + (q8 & 1) * 128 + l15 * 4;

    for (int idx = 0; idx < count; ++idx) {
        const int jt = (jlo >> 6) + idx;
        const size_t tb = ((size_t)(bz * 32 + jt) * 32 + it) * 16 * 256;
        const short* pa = Pm + tb + aoff;
        bf16x4 a00 = *(const bf16x4*)pa;
        bf16x4 a01 = *(const bf16x4*)(pa + 64);
        bf16x4 a10 = *(const bf16x4*)(pa + 2048);
        bf16x4 a11 = *(const bf16x4*)(pa + 2048 + 64);
        bf16x8 a0 = {a00[0], a00[1], a00[2], a00[3], a01[0], a01[1], a01[2], a01[3]};
        bf16x8 a1 = {a10[0], a10[1], a10[2], a10[3], a11[0], a11[1], a11[2], a11[3]};

        const short* vb = vt + (size_t)(bz * 32 + jt) * 8 * 512 + lane * 8;
        #pragma unroll
        for (int ht = 0; ht < 4; ++ht) {
            bf16x8 b0 = *(const bf16x8*)(vb + (ht * 2 + 0) * 512);
            bf16x8 b1 = *(const bf16x8*)(vb + (ht * 2 + 1) * 512);
            oacc[ht] = MFMA(a0, b0, oacc[ht]);
            oacc[ht] = MFMA(a1, b1, oacc[ht]);
        }
    }
    size_t base = ((size_t)(jc * 4 + bz) * kN + i0) * 64;
    #pragma unroll
    for (int ht = 0; ht < 4; ++ht)
        #pragma unroll
        for (int r = 0; r < 4; ++r)
            part[base + (size_t)(16 * w + q8 * 4 + r) * 64 + ht * 16 + l15] = oacc[ht][r];
}

// ---------------------------------------------------------------------------
// reduce: out = sum of 4 jc-chunk partials
// ---------------------------------------------------------------------------
__global__ __launch_bounds__(256) void reduce_kernel(
        const float* __restrict__ part, float* __restrict__ out)
{
    int idx = blockIdx.x * 256 + threadIdx.x;     // 0..131071 float4s
    const float4* p = (const float4*)part;
    float4 a = p[idx];
    float4 b = p[idx + 131072];
    float4 c = p[idx + 262144];
    float4 d = p[idx + 393216];
    float4 r;
    r.x = a.x + b.x + c.x + d.x;
    r.y = a.y + b.y + c.y + d.y;
    r.z = a.z + b.z + c.z + d.z;
    r.w = a.w + b.w + c.w + d.w;
    ((float4*)out)[idx] = r;
}

extern "C" void kernel_launch(void* const* d_in, const int* in_sizes, int n_in,
                              void* d_out, int out_size, void* d_ws, size_t ws_size,
                              hipStream_t stream)
{
    const float* x  = (const float*)d_in[0];
    const float* Wq = (const float*)d_in[1];
    const float* bq = (const float*)d_in[2];
    const float* Wk = (const float*)d_in[3];
    const float* bk = (const float*)d_in[4];
    const float* Wv = (const float*)d_in[5];
    const float* bv = (const float*)d_in[6];
    float* out = (float*)d_out;

    char* base = (char*)d_ws;
    short* Wt   = (short*)(base);                    //    393,216 B
    float* bcat = (float*)(base + 393216);           //      1,024 B
    short* gq   = (short*)(base + 394240);           //  1,179,648 B
    short* gk   = (short*)(base + 1573888);          //  1,179,648 B
    short* vt   = (short*)(base + 2753536);          //  1,048,576 B
    float* l2   = (float*)(base + 3802112);          //    131,072 B
    short* Pm   = (short*)(base + 3933184);          // 33,554,432 B
    float* part = (float*)(base + 37487616);         //  8,388,608 B (~45.9 MB)

    prep_kernel<<<256, 256, 0, stream>>>(Wq, Wk, Wv, bq, bk, bv, Wt, bcat);
    qkv_kernel<<<512, 256, 0, stream>>>(x, Wt, bcat, gq, gk, vt);
    stats_kernel<<<512, 256, 0, stream>>>(gq, gk, l2, Pm);
    vscale_kernel<<<128, 256, 0, stream>>>(vt, l2);
    out_kernel<<<512, 256, 0, stream>>>(Pm, vt, part);
    reduce_kernel<<<512, 256, 0, stream>>>(part, out);
}

// Round 9
// 126.739 us; speedup vs baseline: 1.0076x; 1.0076x over previous
//
#include <hip/hip_runtime.h>
#include <math.h>

// (B,N,D,H) = (4, 2048, 1024, 64)
constexpr int kN = 2048;
constexpr int kD = 1024;

typedef __attribute__((ext_vector_type(8))) short bf16x8;
typedef __attribute__((ext_vector_type(4))) short bf16x4;
typedef __attribute__((ext_vector_type(4))) float f32x4;

#define MFMA(a, b, c) __builtin_amdgcn_mfma_f32_16x16x32_bf16(a, b, c, 0, 0, 0)

__device__ __forceinline__ short f2bf(float f) {
    unsigned u = __float_as_uint(f);
    u += 0x7fff + ((u >> 16) & 1);      // round-to-nearest-even
    return (short)(u >> 16);
}

// global->LDS direct DMA. LDS dest = wave-uniform base + lane*16.
__device__ __forceinline__ void g2l(void* lds, const void* g, int nbytes, int t) {
    int lane = t & 63, w = t >> 6;
    for (int base = w * 1024; base < nbytes; base += 4096) {
        if (base + lane * 16 < nbytes) {
            __builtin_amdgcn_global_load_lds(
                (const __attribute__((address_space(1))) void*)((const char*)g + base + lane * 16),
                (__attribute__((address_space(3))) void*)((char*)lds + base),
                16, 0, 0);
        }
    }
}

// ---------------------------------------------------------------------------
// prep: Wt in MFMA-fragment-contiguous layout; bcat = bq|bk|bv;
// ALSO zeroes d_out (out_kernel accumulates into it atomically).
// ---------------------------------------------------------------------------
__global__ __launch_bounds__(256) void prep_kernel(
        const float* __restrict__ Wq, const float* __restrict__ Wk,
        const float* __restrict__ Wv, const float* __restrict__ bq,
        const float* __restrict__ bk, const float* __restrict__ bv,
        short* __restrict__ Wt, float* __restrict__ bcat,
        float* __restrict__ out)
{
    int tid = blockIdx.x * 256 + threadIdx.x;
    int stride = gridDim.x * 256;
    // zero out: 524288 floats = 131072 float4
    for (int e = tid; e < 131072; e += stride)
        ((float4*)out)[e] = make_float4(0.f, 0.f, 0.f, 0.f);
    for (int e = tid; e < 16 * 12 * 2 * 512; e += stride) {
        int kc = e / 12288;
        int rem = e - kc * 12288;
        int nt = rem >> 10;
        int r2 = rem & 1023;
        int f = r2 >> 9;
        int r3 = r2 & 511;
        int q8 = r3 >> 7;
        int l15 = (r3 >> 3) & 15;
        int el = r3 & 7;
        int n = nt * 16 + l15;
        int d = kc * 64 + f * 32 + q8 * 8 + el;
        float wv = (n < 64) ? Wq[d * 64 + n]
                 : (n < 128) ? Wk[d * 64 + (n - 64)]
                 : Wv[d * 64 + (n - 128)];
        Wt[e] = f2bf(wv);
    }
    if (tid < 192)
        bcat[tid] = (tid < 64) ? bq[tid] : (tid < 128) ? bk[tid - 64] : bv[tid - 128];
}

// ---------------------------------------------------------------------------
// qkv: 512 blocks x 16 rows. x staged to LDS once (no inner barriers); W
// fragments loaded direct global->VGPR (coalesced, L2-resident).
// Outputs: gq/gk[8192][72] bf16, vt[(bz*32+jt)*64+h][72] bf16 (j-local cols).
// ---------------------------------------------------------------------------
constexpr int XP = 1032;   // xs pitch (shorts)

__global__ __launch_bounds__(256) void qkv_kernel(
        const float* __restrict__ x, const short* __restrict__ Wt,
        const float* __restrict__ bcat,
        short* __restrict__ gq, short* __restrict__ gk, short* __restrict__ vt)
{
    __shared__ __align__(16) short xs[16 * XP];    // 33,024 B
    const int t = threadIdx.x;
    const int w = t >> 6, lane = t & 63, l15 = lane & 15, q8 = lane >> 4;
    const int m0 = blockIdx.x * 16;

    // stage x tile (16 rows x 1024), fp32 -> bf16, once
    {
        int row = t >> 4, c4 = (t & 15) * 4;
        const float* xr = x + (size_t)(m0 + row) * kD;
        #pragma unroll
        for (int cc = 0; cc < 16; ++cc) {
            float4 xv = *(const float4*)&xr[cc * 64 + c4];
            bf16x4 pk = {f2bf(xv.x), f2bf(xv.y), f2bf(xv.z), f2bf(xv.w)};
            *(bf16x4*)&xs[row * XP + cc * 64 + c4] = pk;
        }
    }
    __syncthreads();

    f32x4 acc[3];
    #pragma unroll
    for (int ct = 0; ct < 3; ++ct) acc[ct] = (f32x4){0.f, 0.f, 0.f, 0.f};

    #pragma unroll 4
    for (int kc = 0; kc < 16; ++kc) {
        bf16x8 a0 = *(const bf16x8*)&xs[l15 * XP + kc * 64 + q8 * 8];
        bf16x8 a1 = *(const bf16x8*)&xs[l15 * XP + kc * 64 + 32 + q8 * 8];
        #pragma unroll
        for (int ct = 0; ct < 3; ++ct) {
            int nt = w * 3 + ct;
            const short* bp = Wt + ((size_t)(kc * 12 + nt) * 2) * 512 + lane * 8;
            bf16x8 b0 = *(const bf16x8*)bp;
            bf16x8 b1 = *(const bf16x8*)(bp + 512);
            acc[ct] = MFMA(a0, b0, acc[ct]);
            acc[ct] = MFMA(a1, b1, acc[ct]);
        }
    }

    const int bz = m0 >> 11;
    const int jt = (m0 & 2047) >> 6;
    const int jb = m0 & 63;                // 0/16/32/48
    #pragma unroll
    for (int ct = 0; ct < 3; ++ct) {
        int nb2 = w * 48 + ct * 16;        // 16-tile lies in one region
        int n = nb2 + l15;
        float bias = bcat[n];
        if (nb2 < 64) {
            #pragma unroll
            for (int r = 0; r < 4; ++r)
                gq[(size_t)(m0 + q8 * 4 + r) * 72 + n] = f2bf(acc[ct][r] + bias);
        } else if (nb2 < 128) {
            #pragma unroll
            for (int r = 0; r < 4; ++r)
                gk[(size_t)(m0 + q8 * 4 + r) * 72 + (n - 64)] = f2bf(acc[ct][r] + bias);
        } else {
            int h = n - 128;
            bf16x4 pk = {f2bf(acc[ct][0] + bias), f2bf(acc[ct][1] + bias),
                         f2bf(acc[ct][2] + bias), f2bf(acc[ct][3] + bias)};
            *(bf16x4*)&vt[((size_t)((bz * 32 + jt) * 64 + h)) * 72 + jb + q8 * 4] = pk;
        }
    }
}

// ---------------------------------------------------------------------------
// stats: l[j] = sum_{i>=j, s!=0} exp(s/8). Double-buffered k tiles.
// Grid 512: b&3 = i-chunk(512), (b>>2)&3 = bz, b>>4 = j-tile(64). Max 8 iters.
// ---------------------------------------------------------------------------
__global__ __launch_bounds__(256) void stats_kernel(
        const short* __restrict__ gq, const short* __restrict__ gk,
        float* __restrict__ l2)
{
    __shared__ __align__(16) short qsm[64 * 72];
    __shared__ __align__(16) short ksm[2][64 * 72];
    const int t = threadIdx.x;
    const int w = t >> 6, lane = t & 63, l15 = lane & 15, q8 = lane >> 4;
    const int b = blockIdx.x;
    const int ic = b & 3, bz = (b >> 2) & 3, jt = b >> 4;
    const int j0 = jt * 64;
    const int ilo = ic * 512, ihi = ilo + 512;
    const int istart = (j0 > ilo) ? j0 : ilo;
    const int count = (istart < ihi) ? ((ihi - istart) >> 6) : 0;

    float lloc[4] = {0.f, 0.f, 0.f, 0.f};

    if (count > 0) {
        g2l(qsm, gq + (size_t)(bz * kN + j0) * 72, 64 * 144, t);
        g2l(ksm[0], gk + (size_t)(bz * kN + istart) * 72, 64 * 144, t);
        __syncthreads();
        int jrow = 16 * w + l15;
        bf16x8 a0 = *(const bf16x8*)&qsm[jrow * 72 + q8 * 8];
        bf16x8 a1 = *(const bf16x8*)&qsm[jrow * 72 + 32 + q8 * 8];

        for (int idx = 0; idx < count; ++idx) {
            const int cur = idx & 1;
            if (idx + 1 < count)
                g2l(ksm[cur ^ 1],
                    gk + (size_t)(bz * kN + istart + (idx + 1) * 64) * 72, 64 * 144, t);
            const int i0 = istart + idx * 64;
            #pragma unroll
            for (int it = 0; it < 4; ++it) {
                int irow = it * 16 + l15;
                bf16x8 b0 = *(const bf16x8*)&ksm[cur][irow * 72 + q8 * 8];
                bf16x8 b1 = *(const bf16x8*)&ksm[cur][irow * 72 + 32 + q8 * 8];
                f32x4 s = (f32x4){0.f, 0.f, 0.f, 0.f};
                s = MFMA(a0, b0, s);
                s = MFMA(a1, b1, s);
                int ig = i0 + it * 16 + l15;
                #pragma unroll
                for (int r = 0; r < 4; ++r) {
                    int jg = j0 + 16 * w + q8 * 4 + r;
                    float sv = s[r];
                    float e = __expf(sv * 0.125f);
                    lloc[r] += ((ig >= jg) && (sv != 0.0f)) ? e : 0.0f;
                }
            }
            __syncthreads();
        }
    }
    #pragma unroll
    for (int off = 1; off < 16; off <<= 1)
        #pragma unroll
        for (int r = 0; r < 4; ++r)
            lloc[r] += __shfl_xor(lloc[r], off);
    if (l15 == 0) {
        #pragma unroll
        for (int r = 0; r < 4; ++r)
            l2[ic * 8192 + bz * kN + j0 + 16 * w + q8 * 4 + r] = lloc[r];
    }
}

// ---------------------------------------------------------------------------
// out: out[i,h] += sum_{j in jc-chunk, j<=i} exp(s/8)*(1/l[j])*v[j,h]
// Grid 512: b&3 = jc(512-chunk), (b>>2)&3 = bz, b>>4 = i-tile(64). Max 8 iters.
// combine fused (rsm from l2's 4 chunks, double-buffered); q/v double-buffered;
// S recomputed with bit-identical MFMA sequence as stats. Epilogue: atomicAdd
// into pre-zeroed out (replaces part+reduce).
// ---------------------------------------------------------------------------
__global__ __launch_bounds__(256) void out_kernel(
        const short* __restrict__ gq, const short* __restrict__ gk,
        const short* __restrict__ vt, const float* __restrict__ l2,
        float* __restrict__ out)
{
    __shared__ __align__(16) short ksm[64 * 72];
    __shared__ __align__(16) short qsm[2][64 * 72];
    __shared__ __align__(16) short vsm[2][64 * 72];
    __shared__ __align__(16) short psm[64 * 72];
    __shared__ float rsm[2][64];
    const int t = threadIdx.x;
    const int w = t >> 6, lane = t & 63, l15 = lane & 15, q8 = lane >> 4;
    const int b = blockIdx.x;
    const int jc = b & 3, bz = (b >> 2) & 3, it = b >> 4;
    const int i0 = it * 64;
    const int jlo = jc * 512;
    const int jhi = (jlo + 512 < i0 + 64) ? (jlo + 512) : (i0 + 64);
    const int count = (jlo < jhi) ? ((jhi - jlo) >> 6) : 0;

    if (count <= 0) return;   // contributes nothing (out pre-zeroed by prep)

    f32x4 oacc[4];
    #pragma unroll
    for (int i = 0; i < 4; ++i) oacc[i] = (f32x4){0.f, 0.f, 0.f, 0.f};

    g2l(ksm, gk + (size_t)(bz * kN + i0) * 72, 64 * 144, t);
    g2l(qsm[0], gq + (size_t)(bz * kN + jlo) * 72, 64 * 144, t);
    g2l(vsm[0], vt + (size_t)((bz * 32 + (jlo >> 6)) * 64) * 72, 64 * 144, t);
    if (t < 64) {
        int j = bz * kN + jlo + t;
        float l = l2[j] + l2[8192 + j] + l2[16384 + j] + l2[24576 + j];
        rsm[0][t] = (l > 0.f) ? 1.0f / l : 0.0f;
    }
    __syncthreads();

    for (int idx = 0; idx < count; ++idx) {
        const int cur = idx & 1, nb = cur ^ 1;
        const int j0s = jlo + idx * 64;
        if (idx + 1 < count) {
            g2l(qsm[nb], gq + (size_t)(bz * kN + j0s + 64) * 72, 64 * 144, t);
            g2l(vsm[nb], vt + (size_t)((bz * 32 + ((j0s + 64) >> 6)) * 64) * 72,
                64 * 144, t);
            if (t < 64) {
                int j = bz * kN + j0s + 64 + t;
                float l = l2[j] + l2[8192 + j] + l2[16384 + j] + l2[24576 + j];
                rsm[nb][t] = (l > 0.f) ? 1.0f / l : 0.0f;
            }
        }
        // S phase (identical sequence to stats)
        int jrow = 16 * w + l15;
        bf16x8 a0 = *(const bf16x8*)&qsm[cur][jrow * 72 + q8 * 8];
        bf16x8 a1 = *(const bf16x8*)&qsm[cur][jrow * 72 + 32 + q8 * 8];
        #pragma unroll
        for (int itile = 0; itile < 4; ++itile) {
            int irow = itile * 16 + l15;
            bf16x8 b0 = *(const bf16x8*)&ksm[irow * 72 + q8 * 8];
            bf16x8 b1 = *(const bf16x8*)&ksm[irow * 72 + 32 + q8 * 8];
            f32x4 sv4 = (f32x4){0.f, 0.f, 0.f, 0.f};
            sv4 = MFMA(a0, b0, sv4);
            sv4 = MFMA(a1, b1, sv4);
            int ig = i0 + itile * 16 + l15;
            bf16x4 pk;
            #pragma unroll
            for (int r = 0; r < 4; ++r) {
                int jl = 16 * w + q8 * 4 + r;
                int jg = j0s + jl;
                float sv = sv4[r];
                float p = ((ig >= jg) && (sv != 0.0f))
                        ? __expf(sv * 0.125f) * rsm[cur][jl] : 0.0f;
                pk[r] = f2bf(p);
            }
            *(bf16x4*)&psm[(itile * 16 + l15) * 72 + 16 * w + q8 * 4] = pk;
        }
        __syncthreads();   // psm ready; next-tile g2l had S-phase to fly

        // PV phase: A = psm[i-local][j], B = vsm[h][j]
        bf16x8 pa0 = *(const bf16x8*)&psm[(16 * w + l15) * 72 + q8 * 8];
        bf16x8 pa1 = *(const bf16x8*)&psm[(16 * w + l15) * 72 + 32 + q8 * 8];
        #pragma unroll
        for (int ht = 0; ht < 4; ++ht) {
            int vrow = ht * 16 + l15;
            bf16x8 vb0 = *(const bf16x8*)&vsm[cur][vrow * 72 + q8 * 8];
            bf16x8 vb1 = *(const bf16x8*)&vsm[cur][vrow * 72 + 32 + q8 * 8];
            oacc[ht] = MFMA(pa0, vb0, oacc[ht]);
            oacc[ht] = MFMA(pa1, vb1, oacc[ht]);
        }
        __syncthreads();   // protect psm + qsm[cur]/vsm[cur] for next iter
    }

    // accumulate into out (pre-zeroed by prep; <=4 adders per element)
    size_t base = ((size_t)(bz * kN + i0)) * 64;
    #pragma unroll
    for (int ht = 0; ht < 4; ++ht)
        #pragma unroll
        for (int r = 0; r < 4; ++r)
            atomicAdd(&out[base + (size_t)(16 * w + q8 * 4 + r) * 64 + ht * 16 + l15],
                      oacc[ht][r]);
}

extern "C" void kernel_launch(void* const* d_in, const int* in_sizes, int n_in,
                              void* d_out, int out_size, void* d_ws, size_t ws_size,
                              hipStream_t stream)
{
    const float* x  = (const float*)d_in[0];
    const float* Wq = (const float*)d_in[1];
    const float* bq = (const float*)d_in[2];
    const float* Wk = (const float*)d_in[3];
    const float* bk = (const float*)d_in[4];
    const float* Wv = (const float*)d_in[5];
    const float* bv = (const float*)d_in[6];
    float* out = (float*)d_out;

    char* base = (char*)d_ws;
    short* Wt   = (short*)(base);                    //    393,216 B
    float* bcat = (float*)(base + 393216);           //      1,024 B
    short* gq   = (short*)(base + 394240);           //  1,179,648 B
    short* gk   = (short*)(base + 1573888);          //  1,179,648 B
    short* vt   = (short*)(base + 2753536);          //  1,179,648 B
    float* l2   = (float*)(base + 3933184);          //    131,072 B  (~4.1 MB)

    prep_kernel<<<256, 256, 0, stream>>>(Wq, Wk, Wv, bq, bk, bv, Wt, bcat, out);
    qkv_kernel<<<512, 256, 0, stream>>>(x, Wt, bcat, gq, gk, vt);
    stats_kernel<<<512, 256, 0, stream>>>(gq, gk, l2);
    out_kernel<<<512, 256, 0, stream>>>(gq, gk, vt, l2, out);
}